// Round 6
// baseline (95.984 us; speedup 1.0000x reference)
//
#include <hip/hip_runtime.h>

// NonLinearConv2d: ik[b,oc,h,w] = ALPHA * sum_{cin,kh,kw} [ sp2((v-t)/D) - sp2((v-t-VD)/D) ]
//   v = clip(x,0,9) zero-padded patch, t = clip(theta,1,8), sp2(a)=log1p(exp(a))^2
//
// Round 6: 2-node pipeline (was 4).
//  * node 1: vmax_part  -> 64 per-block partial maxima, plain stores (no memset,
//            no atomics). node 2: nlfused does everything else.
//  * nlfused prologue: reduce 64 partials in-register (broadcast load + shuffle);
//    scan this block's 8 ocs of theta; compact active entries into LDS int2
//    lists via LDS atomicAdd (A-tier from bottom of the oc slot, B-tier from
//    top); stage Ev = exp(clip(x)/D) tile in LDS.
//  * hot loop: u = Ev[lds] * Et[lds-list]  -> zero global accesses, zero exp.
//      t >= vmax+0.45  : dropped  (err <= ALPHA*288*0.93*e^-12 ~ 9.2e-7)
//      t >= vmax+0.131 : u<=0.175 quartic series f=u^2(C2-C3u+C4u^2)
//                        (trunc ~0.83u^5 -> ~1.1e-6 output worst-case)
//      else            : exact, 2x __logf
//  * LDS: 17408(Ev) + 18432(lists) + 64 = ~36KB -> 4 blocks/CU, 16 waves/CU.
//  * NOTE (r4 post-mortem): do NOT re-stage atomically-permuted global lists
//    into LDS across kernels; lists here are built+consumed in one kernel
//    (round-1-proven pattern).

#define B_    16
#define CIN_  32
#define H_    32
#define W_    32
#define OC_   64
#define CKK_  288

#define INV_D  13.333333333333334f
#define ALPHA_ 0.0005625f
#define KC     0.26359713811572677f   // e^{-4/3}
#define C2_    0.93051654475128f      // 1 - K^2
#define C3_    0.98168436111127f      // 1 - K^3
#define C4_    0.91224137800000f      // (11/12)(1 - K^4)

#define CUT_DROP 0.45f
#define CUT_A    0.131f

#define WS_NEEDED 256                 // 64 float partials

__device__ __forceinline__ float clipf(float v, float lo, float hi) {
    return fminf(fmaxf(v, lo), hi);
}

__global__ void vmax_part(const float4* __restrict__ x4, float* __restrict__ part, int n4) {
    float m = 0.0f;
    for (int i = blockIdx.x * blockDim.x + threadIdx.x; i < n4; i += gridDim.x * blockDim.x) {
        float4 v = x4[i];
        m = fmaxf(fmaxf(m, clipf(v.x, 0.0f, 9.0f)),
                  fmaxf(clipf(v.y, 0.0f, 9.0f),
                        fmaxf(clipf(v.z, 0.0f, 9.0f), clipf(v.w, 0.0f, 9.0f))));
    }
    #pragma unroll
    for (int off = 32; off > 0; off >>= 1)
        m = fmaxf(m, __shfl_down(m, off, 64));
    __shared__ float sm[4];
    int lane = threadIdx.x & 63, wid = threadIdx.x >> 6;
    if (lane == 0) sm[wid] = m;
    __syncthreads();
    if (threadIdx.x == 0)
        part[blockIdx.x] = fmaxf(fmaxf(sm[0], sm[1]), fmaxf(sm[2], sm[3]));
}

__device__ __forceinline__ float reduce_vmax64(const float* __restrict__ part, int lane) {
    float m = part[lane];                       // 64 floats, L2 broadcast
    #pragma unroll
    for (int off = 32; off > 0; off >>= 1)
        m = fmaxf(m, __shfl_down(m, off, 64));
    return __shfl(m, 0, 64);                    // all lanes get the max
}

__launch_bounds__(256, 4)
__global__ void nlfused(const float* __restrict__ x,
                        const float* __restrict__ theta,
                        const float* __restrict__ part,
                        float* __restrict__ out) {
    __shared__ float sx[CIN_ * 136];    // Ev tile: 32cin x 4row x 34col = 17408 B
    __shared__ int2  sL[8 * CKK_];      // per-oc lists: A from bottom, B from top
    __shared__ int   sCA[8], sCB[8];

    const int blk = blockIdx.x;         // b*128 + rp*8 + ocg
    const int ocg = blk & 7;
    const int rp  = (blk >> 3) & 15;
    const int b   = blk >> 7;
    const int ocbase = ocg * 8;

    if (threadIdx.x < 8) { sCA[threadIdx.x] = 0; sCB[threadIdx.x] = 0; }

    const int lane = threadIdx.x & 63;
    const float vmax = reduce_vmax64(part, lane);
    const float cutB = vmax + CUT_DROP;
    const float cutA = vmax + CUT_A;
    __syncthreads();                    // counters zeroed, visible to all

    // build this block's 8 oc lists in LDS (atomicAdd compaction, r1-proven)
    #pragma unroll
    for (int ol = 0; ol < 8; ++ol) {
        for (int i = threadIdx.x; i < CKK_; i += 256) {
            float t = clipf(theta[(ocbase + ol) * CKK_ + i], 1.0f, 8.0f);
            if (t < cutB) {
                int cin = i / 9;
                int r   = i - cin * 9;
                int2 e;
                e.x = cin * 136 + (r / 3) * 34 + (r % 3);   // Ev tile offset
                e.y = __float_as_int(__expf(-t * INV_D));   // Et
                if (t < cutA) {
                    int idx = atomicAdd(&sCA[ol], 1);
                    sL[ol * CKK_ + idx] = e;                // A: bottom-up
                } else {
                    int idx = atomicAdd(&sCB[ol], 1);
                    sL[ol * CKK_ + (CKK_ - 1) - idx] = e;   // B: top-down
                }
            }
        }
    }

    // stage Ev = exp(clip(x)/D); padded cells -> exp(0)=1
    for (int idx = threadIdx.x; idx < CIN_ * 136; idx += 256) {
        int cin = idx / 136;
        int rem = idx - cin * 136;
        int rr  = rem / 34;
        int cc  = rem - rr * 34;
        int ir  = rp * 2 - 1 + rr;
        int ic  = cc - 1;
        float ev = 1.0f;
        if ((unsigned)ir < (unsigned)H_ && (unsigned)ic < (unsigned)W_)
            ev = __expf(clipf(x[((b * CIN_ + cin) * H_ + ir) * W_ + ic], 0.0f, 9.0f) * INV_D);
        sx[idx] = ev;
    }
    __syncthreads();

    const int wv   = threadIdx.x >> 6;       // wave -> 2-oc subset
    const int rl   = lane >> 5;              // row within the pair
    const int w    = lane & 31;
    const int myoff = rl * 34 + w;
    const int row   = rp * 2 + rl;

    #pragma unroll
    for (int k = 0; k < 2; ++k) {
        const int kk   = wv * 2 + k;
        const int oc   = ocbase + kk;
        const int ca   = sCA[kk];
        const int cb   = sCB[kk];
        const int base = kk * CKK_;

        float accA = 0.0f, accB = 0.0f;

        #pragma unroll 2
        for (int i = 0; i < ca; ++i) {       // exact tier: 2 logs
            const int2 e = sL[base + i];     // wave-uniform -> broadcast
            const float u  = sx[e.x + myoff] * __int_as_float(e.y);
            const float l1 = __logf(1.0f + u);
            const float l2 = __logf(fmaf(u, KC, 1.0f));
            accA += (l1 - l2) * (l1 + l2);
        }
        #pragma unroll 4
        for (int i = CKK_ - cb; i < CKK_; ++i) {   // series tier: no trans
            const int2 e = sL[base + i];
            const float u = sx[e.x + myoff] * __int_as_float(e.y);
            float p = fmaf(u, C4_, -C3_);
            p = fmaf(u, p, C2_);
            accB = fmaf(u * u, p, accB);
        }

        out[((b * OC_ + oc) * H_ + row) * W_ + w] = ALPHA_ * (accA + accB);
    }
}

// ---------- fallback (ws too small): known-correct monolithic kernel ----------
__launch_bounds__(256)
__global__ void nlconv_fallback(const float* __restrict__ x,
                                const float* __restrict__ theta,
                                float* __restrict__ out,
                                const float* __restrict__ part) {
    __shared__ int   s_base[CKK_];
    __shared__ float s_t[CKK_];
    __shared__ int   s_d[CKK_];
    __shared__ int   s_cnt;
    const int blk = blockIdx.x;
    const int b  = blk >> 6;
    const int oc = blk & 63;
    if (threadIdx.x == 0) s_cnt = 0;
    const float vmax = reduce_vmax64(part, threadIdx.x & 63);
    __syncthreads();
    const float cutoff = vmax + 0.6f;
    for (int j = threadIdx.x; j < CKK_; j += blockDim.x) {
        float t = clipf(theta[oc * CKK_ + j], 1.0f, 8.0f);
        if (t < cutoff) {
            int i = atomicAdd(&s_cnt, 1);
            int cin = j / 9;
            int r   = j - cin * 9;
            s_base[i] = cin * (H_ * W_);
            s_t[i]    = t;
            s_d[i]    = (r / 3) | ((r % 3) << 8);
        }
    }
    __syncthreads();
    const int cnt = s_cnt;
    const float* xb = x + b * (CIN_ * H_ * W_);
    const int w  = threadIdx.x & 31;
    const int h0 = threadIdx.x >> 5;
    float acc[4] = {0.f, 0.f, 0.f, 0.f};
    for (int i = 0; i < cnt; ++i) {
        const float t    = s_t[i];
        const int   base = s_base[i];
        const int   d    = s_d[i];
        const int   rdh  = (d & 0xff) - 1;
        const int   rdw  = (d >> 8) - 1;
        const int  col   = w + rdw;
        const bool colok = (unsigned)col < (unsigned)W_;
        const int  ccol  = min(max(col, 0), W_ - 1);
        const float tq   = t * INV_D;
        #pragma unroll
        for (int k = 0; k < 4; ++k) {
            const int  row   = h0 + k * 8 + rdh;
            const bool rowok = (unsigned)row < (unsigned)H_;
            const int  crow  = min(max(row, 0), H_ - 1);
            const float xv   = xb[base + crow * W_ + ccol];
            const float v    = (rowok && colok) ? clipf(xv, 0.0f, 9.0f) : 0.0f;
            const float arg  = fmaf(v, INV_D, -tq);
            const float e1   = __expf(arg);
            const float e2   = e1 * KC;
            const float l1   = __logf(1.0f + e1);
            const float l2   = __logf(1.0f + e2);
            acc[k] += (l1 - l2) * (l1 + l2);
        }
    }
    float* ob = out + (b * OC_ + oc) * (H_ * W_);
    #pragma unroll
    for (int k = 0; k < 4; ++k)
        ob[(h0 + k * 8) * W_ + w] = ALPHA_ * acc[k];
}

extern "C" void kernel_launch(void* const* d_in, const int* in_sizes, int n_in,
                              void* d_out, int out_size, void* d_ws, size_t ws_size,
                              hipStream_t stream) {
    const float* x     = (const float*)d_in[0];
    const float* theta = (const float*)d_in[1];
    float* out  = (float*)d_out;
    float* part = (float*)d_ws;       // 64 partial maxima; every slot written
                                      // by vmax_part each call -> no memset

    const int n4 = (B_ * CIN_ * H_ * W_) / 4;
    vmax_part<<<64, 256, 0, stream>>>((const float4*)x, part, n4);

    if (ws_size >= (size_t)WS_NEEDED) {
        nlfused<<<B_ * 16 * 8, 256, 0, stream>>>(x, theta, part, out);
    } else {
        nlconv_fallback<<<B_ * OC_, 256, 0, stream>>>(x, theta, out, part);
    }
}

// Round 7
// 86.680 us; speedup vs baseline: 1.1073x; 1.1073x over previous
//
#include <hip/hip_runtime.h>

// NonLinearConv2d: ik[b,oc,h,w] = ALPHA * sum_{cin,kh,kw} [ sp2((v-t)/D) - sp2((v-t-VD)/D) ]
//   v = clip(x,0,9) zero-padded patch, t = clip(theta,1,8), sp2(a)=log1p(exp(a))^2
//
// Round 7 = r3 dataflow (proven) + lane-resident lists + readlane broadcast.
//  * u = exp((v-t)/D) = Ev*Et; Ev=exp(v/D) staged in LDS tile; Et=exp(-t/D) in
//    per-oc compacted global lists (separate build_lists kernel, no redundancy).
//  * nlmain: lane i holds list entry i in registers (one dwordx2 load per
//    oc/tier covers <=64 entries; slot is 288 so always in-bounds). Hot loop
//    reads entries via v_readlane (scalar, no memory) -> list latency paid
//    ONCE per oc. ca/cb > 64 falls back to a direct-load tail (correctness
//    without data assumptions).
//  * tiers (r3-validated): t>=vmax+0.6 dropped (err~1.8e-8); t>=vmax+0.131
//    quartic series (u<=0.175, trunc ~1.4e-4 rel on tiny terms); else 2x logf.
//  * vmax: 64 plain-stored partials (no memset node, r6-proven), reduced
//    in-register by consumers. 3 graph nodes total.
//  * r4 lesson: no cross-kernel LDS re-staging of atomically-permuted lists.
//  * r6 lesson: no fused per-block list building (256x redundant, serialized).

#define B_    16
#define CIN_  32
#define H_    32
#define W_    32
#define OC_   64
#define CKK_  288

#define INV_D  13.333333333333334f
#define ALPHA_ 0.0005625f
#define KC     0.26359713811572677f   // e^{-4/3}
#define C2_    0.93051654475128f      // 1 - K^2
#define C3_    0.98168436111127f      // 1 - K^3
#define C4_    0.91224137800000f      // (11/12)(1 - K^4)

// ws layout (bytes)
#define WS_PART   0                           // 64 float partial maxima
#define WS_CNTA   256
#define WS_CNTB   512
#define WS_LISTA  1024                        // int2[64][288]
#define WS_LISTB  (1024 + 64*288*8)
#define WS_NEEDED (WS_LISTB + 64*288*8)       // 295936

__device__ __forceinline__ float clipf(float v, float lo, float hi) {
    return fminf(fmaxf(v, lo), hi);
}

__global__ void vmax_part(const float4* __restrict__ x4, float* __restrict__ part, int n4) {
    float m = 0.0f;
    for (int i = blockIdx.x * blockDim.x + threadIdx.x; i < n4; i += gridDim.x * blockDim.x) {
        float4 v = x4[i];
        m = fmaxf(fmaxf(m, clipf(v.x, 0.0f, 9.0f)),
                  fmaxf(clipf(v.y, 0.0f, 9.0f),
                        fmaxf(clipf(v.z, 0.0f, 9.0f), clipf(v.w, 0.0f, 9.0f))));
    }
    #pragma unroll
    for (int off = 32; off > 0; off >>= 1)
        m = fmaxf(m, __shfl_down(m, off, 64));
    __shared__ float sm[4];
    int lane = threadIdx.x & 63, wid = threadIdx.x >> 6;
    if (lane == 0) sm[wid] = m;
    __syncthreads();
    if (threadIdx.x == 0)
        part[blockIdx.x] = fmaxf(fmaxf(sm[0], sm[1]), fmaxf(sm[2], sm[3]));
}

__device__ __forceinline__ float reduce_vmax64(const float* __restrict__ part, int lane) {
    float m = part[lane];                       // 64 floats, L2 broadcast
    #pragma unroll
    for (int off = 32; off > 0; off >>= 1)
        m = fmaxf(m, __shfl_down(m, off, 64));
    return __shfl(m, 0, 64);
}

__global__ void build_lists(const float* __restrict__ theta,
                            const float* __restrict__ part,
                            int* __restrict__ cntA, int* __restrict__ cntB,
                            int2* __restrict__ listA, int2* __restrict__ listB) {
    __shared__ int sA, sB;
    if (threadIdx.x == 0) { sA = 0; sB = 0; }
    const float vmax = reduce_vmax64(part, threadIdx.x & 63);
    __syncthreads();
    const int oc = blockIdx.x;
    const float cutB = vmax + 0.6f;
    const float cutA = vmax + 0.131f;   // u <= 0.175 beyond this
    for (int j = threadIdx.x; j < CKK_; j += blockDim.x) {
        float t = clipf(theta[oc * CKK_ + j], 1.0f, 8.0f);
        if (t < cutB) {
            int cin = j / 9;
            int r   = j - cin * 9;
            int2 e;
            e.x = cin * 136 + (r / 3) * 34 + (r % 3);   // Ev-tile offset
            e.y = __float_as_int(__expf(-t * INV_D));   // Et
            if (t < cutA) { int i = atomicAdd(&sA, 1); listA[oc * CKK_ + i] = e; }
            else          { int i = atomicAdd(&sB, 1); listB[oc * CKK_ + i] = e; }
        }
    }
    __syncthreads();
    if (threadIdx.x == 0) { cntA[oc] = sA; cntB[oc] = sB; }
}

__launch_bounds__(256, 4)
__global__ void nlmain(const float* __restrict__ x,
                       const int* __restrict__ cntA, const int* __restrict__ cntB,
                       const int2* __restrict__ listA, const int2* __restrict__ listB,
                       float* __restrict__ out) {
    __shared__ float sx[CIN_ * 136];   // Ev tile: 32cin x 4row x 34col = 17408 B

    const int blk = blockIdx.x;        // b*64 + rp*4 + ocg
    const int ocg = blk & 3;
    const int rp  = (blk >> 2) & 15;
    const int b   = blk >> 6;

    const int lane = threadIdx.x & 63;
    const int wv   = threadIdx.x >> 6;       // wave -> 4-oc subset
    const int ocbase = ocg * 16 + wv * 4;

    // prefetch: counts + lane-resident list entries for this wave's 4 ocs.
    // lane i holds entry i; slot is 288 entries so lane-indexed load is
    // always in-bounds regardless of ca/cb.
    int  caV[4], cbV[4];
    int2 eA[4], eB[4];
    #pragma unroll
    for (int k = 0; k < 4; ++k) {
        const int oc = ocbase + k;
        caV[k] = cntA[oc];
        cbV[k] = cntB[oc];
        eA[k]  = listA[oc * CKK_ + lane];
        eB[k]  = listB[oc * CKK_ + lane];
    }

    // stage Ev = exp(clip(x)/D); padded cells -> exp(0)=1
    for (int idx = threadIdx.x; idx < CIN_ * 136; idx += 256) {
        int cin = idx / 136;
        int rem = idx - cin * 136;
        int rr  = rem / 34;
        int cc  = rem - rr * 34;
        int ir  = rp * 2 - 1 + rr;
        int ic  = cc - 1;
        float ev = 1.0f;
        if ((unsigned)ir < (unsigned)H_ && (unsigned)ic < (unsigned)W_)
            ev = __expf(clipf(x[((b * CIN_ + cin) * H_ + ir) * W_ + ic], 0.0f, 9.0f) * INV_D);
        sx[idx] = ev;
    }
    __syncthreads();

    const int rl    = lane >> 5;             // row within the pair
    const int w     = lane & 31;
    const int myoff = rl * 34 + w;
    const int row   = rp * 2 + rl;

    #pragma unroll
    for (int k = 0; k < 4; ++k) {
        const int oc = ocbase + k;
        const int ca = caV[k];
        const int cb = cbV[k];
        const int caR = min(ca, 64);
        const int cbR = min(cb, 64);

        float accA = 0.0f, accB = 0.0f;

        #pragma unroll 2
        for (int i = 0; i < caR; ++i) {      // exact tier: 2 logs
            const int   off = __builtin_amdgcn_readlane(eA[k].x, i);
            const float Et  = __int_as_float(__builtin_amdgcn_readlane(eA[k].y, i));
            const float u   = sx[off + myoff] * Et;
            const float l1  = __logf(1.0f + u);
            const float l2  = __logf(fmaf(u, KC, 1.0f));
            accA += (l1 - l2) * (l1 + l2);
        }
        #pragma unroll 4
        for (int i = 0; i < cbR; ++i) {      // series tier: no transcendentals
            const int   off = __builtin_amdgcn_readlane(eB[k].x, i);
            const float Et  = __int_as_float(__builtin_amdgcn_readlane(eB[k].y, i));
            const float u   = sx[off + myoff] * Et;
            float p = fmaf(u, C4_, -C3_);
            p = fmaf(u, p, C2_);
            accB = fmaf(u * u, p, accB);
        }

        // correctness tails for ca/cb > 64 (not expected with uniform theta,
        // but must not depend on data)
        for (int i = 64; i < ca; ++i) {
            const int2 e = listA[oc * CKK_ + i];
            const float u  = sx[e.x + myoff] * __int_as_float(e.y);
            const float l1 = __logf(1.0f + u);
            const float l2 = __logf(fmaf(u, KC, 1.0f));
            accA += (l1 - l2) * (l1 + l2);
        }
        for (int i = 64; i < cb; ++i) {
            const int2 e = listB[oc * CKK_ + i];
            const float u = sx[e.x + myoff] * __int_as_float(e.y);
            float p = fmaf(u, C4_, -C3_);
            p = fmaf(u, p, C2_);
            accB = fmaf(u * u, p, accB);
        }

        out[((b * OC_ + oc) * H_ + row) * W_ + w] = ALPHA_ * (accA + accB);
    }
}

// ---------- fallback (ws too small): known-correct monolithic kernel ----------
__launch_bounds__(256)
__global__ void nlconv_fallback(const float* __restrict__ x,
                                const float* __restrict__ theta,
                                float* __restrict__ out,
                                const float* __restrict__ part) {
    __shared__ int   s_base[CKK_];
    __shared__ float s_t[CKK_];
    __shared__ int   s_d[CKK_];
    __shared__ int   s_cnt;
    const int blk = blockIdx.x;
    const int b  = blk >> 6;
    const int oc = blk & 63;
    if (threadIdx.x == 0) s_cnt = 0;
    const float vmax = reduce_vmax64(part, threadIdx.x & 63);
    __syncthreads();
    const float cutoff = vmax + 0.6f;
    for (int j = threadIdx.x; j < CKK_; j += blockDim.x) {
        float t = clipf(theta[oc * CKK_ + j], 1.0f, 8.0f);
        if (t < cutoff) {
            int i = atomicAdd(&s_cnt, 1);
            int cin = j / 9;
            int r   = j - cin * 9;
            s_base[i] = cin * (H_ * W_);
            s_t[i]    = t;
            s_d[i]    = (r / 3) | ((r % 3) << 8);
        }
    }
    __syncthreads();
    const int cnt = s_cnt;
    const float* xb = x + b * (CIN_ * H_ * W_);
    const int w  = threadIdx.x & 31;
    const int h0 = threadIdx.x >> 5;
    float acc[4] = {0.f, 0.f, 0.f, 0.f};
    for (int i = 0; i < cnt; ++i) {
        const float t    = s_t[i];
        const int   base = s_base[i];
        const int   d    = s_d[i];
        const int   rdh  = (d & 0xff) - 1;
        const int   rdw  = (d >> 8) - 1;
        const int  col   = w + rdw;
        const bool colok = (unsigned)col < (unsigned)W_;
        const int  ccol  = min(max(col, 0), W_ - 1);
        const float tq   = t * INV_D;
        #pragma unroll
        for (int k = 0; k < 4; ++k) {
            const int  row   = h0 + k * 8 + rdh;
            const bool rowok = (unsigned)row < (unsigned)H_;
            const int  crow  = min(max(row, 0), H_ - 1);
            const float xv   = xb[base + crow * W_ + ccol];
            const float v    = (rowok && colok) ? clipf(xv, 0.0f, 9.0f) : 0.0f;
            const float arg  = fmaf(v, INV_D, -tq);
            const float e1   = __expf(arg);
            const float e2   = e1 * KC;
            const float l1   = __logf(1.0f + e1);
            const float l2   = __logf(1.0f + e2);
            acc[k] += (l1 - l2) * (l1 + l2);
        }
    }
    float* ob = out + (b * OC_ + oc) * (H_ * W_);
    #pragma unroll
    for (int k = 0; k < 4; ++k)
        ob[(h0 + k * 8) * W_ + w] = ALPHA_ * acc[k];
}

extern "C" void kernel_launch(void* const* d_in, const int* in_sizes, int n_in,
                              void* d_out, int out_size, void* d_ws, size_t ws_size,
                              hipStream_t stream) {
    const float* x     = (const float*)d_in[0];
    const float* theta = (const float*)d_in[1];
    float* out = (float*)d_out;
    char* ws = (char*)d_ws;

    float* part = (float*)(ws + WS_PART);   // all 64 slots plain-stored each call

    const int n4 = (B_ * CIN_ * H_ * W_) / 4;
    vmax_part<<<64, 256, 0, stream>>>((const float4*)x, part, n4);

    if (ws_size >= (size_t)WS_NEEDED) {
        int*  cntA  = (int*)(ws + WS_CNTA);
        int*  cntB  = (int*)(ws + WS_CNTB);
        int2* listA = (int2*)(ws + WS_LISTA);
        int2* listB = (int2*)(ws + WS_LISTB);

        build_lists<<<OC_, 128, 0, stream>>>(theta, part, cntA, cntB, listA, listB);
        nlmain<<<B_ * 16 * 4, 256, 0, stream>>>(x, cntA, cntB, listA, listB, out);
    } else {
        nlconv_fallback<<<B_ * OC_, 256, 0, stream>>>(x, theta, out, part);
    }
}